// Round 1
// baseline (961.661 us; speedup 1.0000x reference)
//
#include <hip/hip_runtime.h>

#define Bn 4
#define Sn 4096
#define Dn 1024
#define En 8
#define Cn 1024
#define Fn 2048
#define Mn (Bn * Cn) // 4096 rows per expert (all batches)

typedef __bf16 bf16x4 __attribute__((ext_vector_type(4)));
typedef __bf16 bf16x8 __attribute__((ext_vector_type(8)));
typedef float f32x4 __attribute__((ext_vector_type(4)));

// LDS tile: [128 rows][32 k] bf16, XOR swizzle on element index (16B-block
// granularity) to kill ds_read_b128 bank conflicts (G4 / T2 recipe).
__device__ __forceinline__ int swz32(int row, int k) {
  return ((row << 5) + k) ^ ((row & 7) << 3);
}

// ---- transpose + cast: in[e][K][N] f32  ->  out[e][N][K] bf16 ----
__global__ __launch_bounds__(256) void tcast_kernel(
    const float* __restrict__ in, __bf16* __restrict__ out, int K, int N) {
  __shared__ float t[32][33];
  const int e = blockIdx.z;
  const float* src = in + (size_t)e * K * N;
  __bf16* dst = out + (size_t)e * K * N;
  const int n0 = blockIdx.x << 5, k0 = blockIdx.y << 5;
  const int tx = threadIdx.x & 31, ty = threadIdx.x >> 5;
#pragma unroll
  for (int i = 0; i < 4; ++i)
    t[ty + i * 8][tx] = src[(size_t)(k0 + ty + i * 8) * N + (n0 + tx)];
  __syncthreads();
#pragma unroll
  for (int i = 0; i < 4; ++i)
    dst[(size_t)(n0 + ty + i * 8) * K + (k0 + tx)] = (__bf16)t[tx][ty + i * 8];
}

// ---- fused gather + GEMM(w1) + GEMM(w2) + SwiGLU -> Hb bf16 [E][Mn][Fn] ----
__global__ __launch_bounds__(256) void gemm12_kernel(
    const float* __restrict__ x, const int* __restrict__ tok,
    const __bf16* __restrict__ w1T, const __bf16* __restrict__ w2T,
    __bf16* __restrict__ Hb) {
  __shared__ __bf16 As[2][128 * 32];
  __shared__ __bf16 B1s[2][128 * 32];
  __shared__ __bf16 B2s[2][128 * 32];
  __shared__ int smTok[128];

  const int tid = threadIdx.x;
  const int lane = tid & 63, wid = tid >> 6;
  const int wm = wid >> 1, wn = wid & 1;
  const int e = blockIdx.y;
  const int mt = blockIdx.x & 31; // M/128 = 32
  const int nt = blockIdx.x >> 5; // F/128 = 16
  const int b = mt >> 3;          // 128-row tile lies within one batch row

  if (tid < 128) {
    int c = ((mt << 7) + tid) & (Cn - 1);
    smTok[tid] = tok[((size_t)b * En + e) * Cn + c];
  }
  __syncthreads();

  const int srow = tid >> 1;         // staging row 0..127
  const int skof = (tid & 1) << 4;   // k offset 0 / 16

  const float* aBase = x + ((size_t)b * Sn + smTok[srow]) * Dn + skof;
  const __bf16* b1Base = w1T + ((size_t)e * Fn + (nt << 7) + srow) * Dn + skof;
  const __bf16* b2Base = w2T + ((size_t)e * Fn + (nt << 7) + srow) * Dn + skof;

  f32x4 acc1[4][4], acc2[4][4];
  const f32x4 z4 = {0.f, 0.f, 0.f, 0.f};
#pragma unroll
  for (int i = 0; i < 4; ++i)
#pragma unroll
    for (int j = 0; j < 4; ++j) {
      acc1[i][j] = z4;
      acc2[i][j] = z4;
    }

  f32x4 aReg[4];
  bf16x8 b1Reg[2], b2Reg[2];

  auto loadRegs = [&](int kt) {
    const float* ap = aBase + (kt << 5);
#pragma unroll
    for (int i = 0; i < 4; ++i) aReg[i] = *(const f32x4*)(ap + (i << 2));
    const __bf16* p1 = b1Base + (kt << 5);
    const __bf16* p2 = b2Base + (kt << 5);
#pragma unroll
    for (int i = 0; i < 2; ++i) {
      b1Reg[i] = *(const bf16x8*)(p1 + (i << 3));
      b2Reg[i] = *(const bf16x8*)(p2 + (i << 3));
    }
  };
  auto writeLDS = [&](int buf) {
#pragma unroll
    for (int i = 0; i < 4; ++i) {
      bf16x4 v;
      v[0] = (__bf16)aReg[i][0];
      v[1] = (__bf16)aReg[i][1];
      v[2] = (__bf16)aReg[i][2];
      v[3] = (__bf16)aReg[i][3];
      *(bf16x4*)&As[buf][swz32(srow, skof + (i << 2))] = v;
    }
#pragma unroll
    for (int i = 0; i < 2; ++i) {
      *(bf16x8*)&B1s[buf][swz32(srow, skof + (i << 3))] = b1Reg[i];
      *(bf16x8*)&B2s[buf][swz32(srow, skof + (i << 3))] = b2Reg[i];
    }
  };
  auto doMfma = [&](int buf) {
    const int rr = lane & 15, kk = (lane >> 4) << 3;
    bf16x8 af[4], b1f[4], b2f[4];
#pragma unroll
    for (int i = 0; i < 4; ++i) {
      af[i] = *(const bf16x8*)&As[buf][swz32((wm << 6) + (i << 4) + rr, kk)];
      b1f[i] = *(const bf16x8*)&B1s[buf][swz32((wn << 6) + (i << 4) + rr, kk)];
      b2f[i] = *(const bf16x8*)&B2s[buf][swz32((wn << 6) + (i << 4) + rr, kk)];
    }
#pragma unroll
    for (int fm = 0; fm < 4; ++fm)
#pragma unroll
      for (int fn = 0; fn < 4; ++fn) {
        acc1[fm][fn] = __builtin_amdgcn_mfma_f32_16x16x32_bf16(
            af[fm], b1f[fn], acc1[fm][fn], 0, 0, 0);
        acc2[fm][fn] = __builtin_amdgcn_mfma_f32_16x16x32_bf16(
            af[fm], b2f[fn], acc2[fm][fn], 0, 0, 0);
      }
  };

  loadRegs(0);
#pragma unroll 1
  for (int kt = 0; kt < 32; kt += 2) {
    writeLDS(0);
    __syncthreads();
    loadRegs(kt + 1);
    doMfma(0);
    writeLDS(1);
    __syncthreads();
    if (kt + 2 < 32) loadRegs(kt + 2);
    doMfma(1);
  }

  // epilogue: h = silu(g) * v, store bf16
  __bf16* hOut =
      Hb + ((size_t)e * Mn + (mt << 7) + (wm << 6)) * Fn + (nt << 7) + (wn << 6);
  const int rb = (lane >> 4) << 2, cb = lane & 15;
#pragma unroll
  for (int fm = 0; fm < 4; ++fm)
#pragma unroll
    for (int fn = 0; fn < 4; ++fn)
#pragma unroll
      for (int j = 0; j < 4; ++j) {
        float g = acc1[fm][fn][j];
        float v = acc2[fm][fn][j];
        float h = (g / (1.f + __expf(-g))) * v;
        hOut[(size_t)((fm << 4) + rb + j) * Fn + (fn << 4) + cb] = (__bf16)h;
      }
}

// ---- GEMM3: Hb x w3T -> scale by expert weight -> atomic scatter-add ----
__global__ __launch_bounds__(256) void gemm3_kernel(
    const __bf16* __restrict__ Hb, const __bf16* __restrict__ w3T,
    const int* __restrict__ tok, const float* __restrict__ ew,
    float* __restrict__ out) {
  __shared__ __bf16 As[2][128 * 32];
  __shared__ __bf16 Bs[2][128 * 32];

  const int tid = threadIdx.x;
  const int lane = tid & 63, wid = tid >> 6;
  const int wm = wid >> 1, wn = wid & 1;
  const int e = blockIdx.y;
  const int mt = blockIdx.x & 31; // M/128 = 32
  const int nt = blockIdx.x >> 5; // D/128 = 8

  const int srow = tid >> 1;
  const int skof = (tid & 1) << 4;

  const __bf16* aBase = Hb + ((size_t)e * Mn + (mt << 7) + srow) * Fn + skof;
  const __bf16* bBase = w3T + ((size_t)e * Dn + (nt << 7) + srow) * Fn + skof;

  f32x4 acc[4][4];
  const f32x4 z4 = {0.f, 0.f, 0.f, 0.f};
#pragma unroll
  for (int i = 0; i < 4; ++i)
#pragma unroll
    for (int j = 0; j < 4; ++j) acc[i][j] = z4;

  bf16x8 aReg[2], bReg[2];

  auto loadRegs = [&](int kt) {
#pragma unroll
    for (int i = 0; i < 2; ++i) {
      aReg[i] = *(const bf16x8*)(aBase + (kt << 5) + (i << 3));
      bReg[i] = *(const bf16x8*)(bBase + (kt << 5) + (i << 3));
    }
  };
  auto writeLDS = [&](int buf) {
#pragma unroll
    for (int i = 0; i < 2; ++i) {
      *(bf16x8*)&As[buf][swz32(srow, skof + (i << 3))] = aReg[i];
      *(bf16x8*)&Bs[buf][swz32(srow, skof + (i << 3))] = bReg[i];
    }
  };
  auto doMfma = [&](int buf) {
    const int rr = lane & 15, kk = (lane >> 4) << 3;
    bf16x8 af[4], bf4[4];
#pragma unroll
    for (int i = 0; i < 4; ++i) {
      af[i] = *(const bf16x8*)&As[buf][swz32((wm << 6) + (i << 4) + rr, kk)];
      bf4[i] = *(const bf16x8*)&Bs[buf][swz32((wn << 6) + (i << 4) + rr, kk)];
    }
#pragma unroll
    for (int fm = 0; fm < 4; ++fm)
#pragma unroll
      for (int fn = 0; fn < 4; ++fn)
        acc[fm][fn] = __builtin_amdgcn_mfma_f32_16x16x32_bf16(
            af[fm], bf4[fn], acc[fm][fn], 0, 0, 0);
  };

  loadRegs(0);
#pragma unroll 1
  for (int kt = 0; kt < 64; kt += 2) { // K = F = 2048
    writeLDS(0);
    __syncthreads();
    loadRegs(kt + 1);
    doMfma(0);
    writeLDS(1);
    __syncthreads();
    if (kt + 2 < 64) loadRegs(kt + 2);
    doMfma(1);
  }

  // epilogue: weighted atomic scatter-add into out[b, tok, :]
  const int b = mt >> 3;
  const int rowBase = (mt << 7) + (wm << 6);
  const int colBase = (nt << 7) + (wn << 6) + (lane & 15);
  const int rb = (lane >> 4) << 2;
#pragma unroll
  for (int fm = 0; fm < 4; ++fm) {
#pragma unroll
    for (int j = 0; j < 4; ++j) {
      int r = rowBase + (fm << 4) + rb + j;
      int c = r & (Cn - 1);
      size_t ix = ((size_t)b * En + e) * Cn + c;
      int t = tok[ix];
      float w = ew[ix];
      float* orow = out + ((size_t)b * Sn + t) * Dn + colBase;
#pragma unroll
      for (int fn = 0; fn < 4; ++fn)
        atomicAdd(orow + (fn << 4), acc[fm][fn][j] * w);
    }
  }
}

extern "C" void kernel_launch(void* const* d_in, const int* in_sizes, int n_in,
                              void* d_out, int out_size, void* d_ws,
                              size_t ws_size, hipStream_t stream) {
  const float* x = (const float*)d_in[0];
  const float* ew = (const float*)d_in[1];
  const int* tok = (const int*)d_in[2];
  const float* w1 = (const float*)d_in[3];
  const float* w2 = (const float*)d_in[4];
  const float* w3 = (const float*)d_in[5];
  float* out = (float*)d_out;

  const size_t wE = (size_t)En * Dn * Fn; // 16,777,216 elems per weight
  __bf16* w1T = (__bf16*)d_ws;
  __bf16* w2T = w1T + wE;
  __bf16* w3T = w2T + wE;
  __bf16* Hb = w3T + wE;
  const size_t need = (3 * wE + (size_t)En * Mn * Fn) * sizeof(__bf16);
  if (ws_size < need) return; // fail loudly (output stays poisoned)

  (void)hipMemsetAsync(d_out, 0, (size_t)Bn * Sn * Dn * sizeof(float), stream);

  tcast_kernel<<<dim3(Fn / 32, Dn / 32, En), 256, 0, stream>>>(w1, w1T, Dn, Fn);
  tcast_kernel<<<dim3(Fn / 32, Dn / 32, En), 256, 0, stream>>>(w2, w2T, Dn, Fn);
  tcast_kernel<<<dim3(Dn / 32, Fn / 32, En), 256, 0, stream>>>(w3, w3T, Fn, Dn);
  gemm12_kernel<<<dim3(512, En), 256, 0, stream>>>(x, tok, w1T, w2T, Hb);
  gemm3_kernel<<<dim3(256, En), 256, 0, stream>>>(Hb, w3T, tok, ew, out);
}